// Round 5
// baseline (109.380 us; speedup 1.0000x reference)
//
#include <hip/hip_runtime.h>
#include <hip/hip_bf16.h>

#define MIN_PTS 4

typedef short bf16x8 __attribute__((ext_vector_type(8)));
typedef float f32x4  __attribute__((ext_vector_type(4)));

__device__ __forceinline__ ushort f2bf(float x) {
    unsigned u = __float_as_uint(x);
    u = (u + 0x7fffu + ((u >> 16) & 1u)) >> 16;   // RNE, finite inputs
    return (ushort)u;
}

// v_cvt_pk_bf16_f32: lo -> low 16, hi -> high 16 (RNE)
__device__ __forceinline__ uint cvt_pk_bf16(float lo, float hi) {
    union { __hip_bfloat162 h; uint u; } cv;
    cv.h = __float22bfloat162_rn(make_float2(lo, hi));
    return cv.u;
}

// Pack W2 [64][128] and W3 [128][256] (fp32 row-major, K x N) into bf16
// MFMA B-fragment-linear layout: [ntile][kstep][lane][8], where
// element j of lane l = W[k = 32*ks + 8*(l>>4) + j][col = 16*nt + (l&15)].
__global__ void pack_weights(const float* __restrict__ W2, const float* __restrict__ W3,
                             ushort* __restrict__ B2P, ushort* __restrict__ B3P)
{
    int idx = blockIdx.x * 256 + threadIdx.x;
    if (idx < 8192) {   // W2: 8 ntiles x 2 ksteps x 64 lanes x 8
        int j = idx & 7, l = (idx >> 3) & 63, ks = (idx >> 9) & 1, nt = idx >> 10;
        int k   = ks * 32 + (l >> 4) * 8 + j;
        int col = nt * 16 + (l & 15);
        B2P[idx] = f2bf(W2[k * 128 + col]);
    }
    if (idx < 32768) {  // W3: 16 ntiles x 4 ksteps x 64 lanes x 8
        int j = idx & 7, l = (idx >> 3) & 63, ks = (idx >> 9) & 3, nt = idx >> 11;
        int k   = ks * 32 + (l >> 4) * 8 + j;
        int col = nt * 16 + (l & 15);
        B3P[idx] = f2bf(W3[k * 256 + col]);
    }
}

// Persistent grid-stride blocks (8 waves, 512 thr). One work item = one
// 64-point stripe: q -> p = q>>2, s = q&3. Wave w: layer1 features 8w..8w+7;
// layer2 ntile w; layer3 ntiles {2w, 2w+1}.
__global__ __launch_bounds__(512, 8) void refine_loop(
    const float* __restrict__ points,    // [P][N][3]
    const int*   __restrict__ lengths,   // [P]
    const float* __restrict__ proposals, // [P][6]
    const float* __restrict__ W1, const float* __restrict__ b1,   // [3][64],[64]
    const float* __restrict__ b2,                                  // [128]
    const float* __restrict__ b3,                                  // [256]
    const ushort* __restrict__ B2P, const ushort* __restrict__ B3P,
    int* __restrict__ featsG,            // [P][256] f32 bits, pre-zeroed
    int P, int N, int work, int NB)
{
    __shared__ __align__(16) ushort A1[4096];   // h1 frags [mt(4)][ks(2)][lane][8]
    __shared__ __align__(16) ushort A3[8192];   // h2 frags [mt(4)][ks(4)][lane][8]

    const int tid  = threadIdx.x;
    const int lane = tid & 63;
    const int wu   = __builtin_amdgcn_readfirstlane(tid >> 6);  // wave id, SGPR
    const int rc   = lane & 15;
    const int g    = lane >> 4;

    // ---- loop-invariant state ----
    // layer-1 weights: wave-uniform -> scalar loads, SGPR-resident
    float w1a[8], w1b[8], w1c[8], b1r[8];
    #pragma unroll
    for (int i = 0; i < 8; ++i) {
        const int f = wu * 8 + i;
        w1a[i] = W1[f]; w1b[i] = W1[64 + f]; w1c[i] = W1[128 + f]; b1r[i] = b1[f];
    }
    // per-lane biases (folded into MFMA C-init)
    f32x4 bias2q;
    #pragma unroll
    for (int rr = 0; rr < 4; ++rr) bias2q[rr] = b2[16 * wu + 4 * g + rr];
    const float b3v0 = b3[16 * (2 * wu + 0) + rc];
    const float b3v1 = b3[16 * (2 * wu + 1) + rc];
    // layer-2 weight fragments, persistent in VGPR
    bf16x8 bw2[2];
    #pragma unroll
    for (int ks = 0; ks < 2; ++ks)
        bw2[ks] = *(const bf16x8*)(B2P + ((wu * 2 + ks) * 64 + lane) * 8);

    // iteration-invariant LDS addresses
    ushort* const a1wr = &A1[(((lane >> 4) * 2 + (wu >> 2)) * 64 + (wu & 3) * 16 + rc) * 8];
    const int ks3 = wu >> 1;                 // (16w+4g)>>5
    const int g3  = (2 * wu + (g >> 1)) & 3; // ((16w+4g)>>3)&3

    // ---- prefetch item q ----
    int q = blockIdx.x;
    int   lenC;
    float cxC, cyC, czC, rxC, ryC, rzC, p0C, p1C, p2C;
    {
        const int pp = q >> 2, ss = q & 3;
        lenC = lengths[pp];
        cxC = proposals[pp * 6 + 0]; cyC = proposals[pp * 6 + 1]; czC = proposals[pp * 6 + 2];
        rxC = __builtin_amdgcn_rcpf(fmaf(proposals[pp * 6 + 3], 0.5f, 1e-6f));
        ryC = __builtin_amdgcn_rcpf(fmaf(proposals[pp * 6 + 4], 0.5f, 1e-6f));
        rzC = __builtin_amdgcn_rcpf(fmaf(proposals[pp * 6 + 5], 0.5f, 1e-6f));
        const int jj = min(ss * 64 + lane, max(lenC, 1) - 1);
        const float* pt = points + ((long)pp * N + jj) * 3;
        p0C = pt[0]; p1C = pt[1]; p2C = pt[2];
    }

    while (q < work) {
        const int   pcur = q >> 2;
        const bool  active = (lenC >= MIN_PTS) && ((q & 3) * 64 < lenC);
        const float cx = cxC, cy = cyC, cz = czC, rx = rxC, ry = ryC, rz = rzC;
        const float p0 = p0C, p1 = p1C, p2 = p2C;

        const int qn = q + NB;
        if (qn < work) {   // prefetch next item (hides under MFMA phases)
            const int pp = qn >> 2, ss = qn & 3;
            lenC = lengths[pp];
            cxC = proposals[pp * 6 + 0]; cyC = proposals[pp * 6 + 1]; czC = proposals[pp * 6 + 2];
            rxC = __builtin_amdgcn_rcpf(fmaf(proposals[pp * 6 + 3], 0.5f, 1e-6f));
            ryC = __builtin_amdgcn_rcpf(fmaf(proposals[pp * 6 + 4], 0.5f, 1e-6f));
            rzC = __builtin_amdgcn_rcpf(fmaf(proposals[pp * 6 + 5], 0.5f, 1e-6f));
            const int jj = min(ss * 64 + lane, max(lenC, 1) - 1);
            const float* pt = points + ((long)pp * N + jj) * 3;
            p0C = pt[0]; p1C = pt[1]; p2C = pt[2];
        }

        if (active) {   // block-uniform branch (q is block-uniform)
            // ---------- Phase A: layer 1 (3->64), one uint4 LDS write/lane ----------
            {
                const float x0 = (p0 - cx) * rx;
                const float x1 = (p1 - cy) * ry;
                const float x2 = (p2 - cz) * rz;
                float v[8];
                #pragma unroll
                for (int i = 0; i < 8; ++i)
                    v[i] = fmaxf(fmaf(x0, w1a[i], fmaf(x1, w1b[i], fmaf(x2, w1c[i], b1r[i]))), 0.f);
                uint4 qq;
                qq.x = cvt_pk_bf16(v[0], v[1]);
                qq.y = cvt_pk_bf16(v[2], v[3]);
                qq.z = cvt_pk_bf16(v[4], v[5]);
                qq.w = cvt_pk_bf16(v[6], v[7]);
                *(uint4*)a1wr = qq;
            }
            __syncthreads();

            // ---------- Phase B: layer 2 (64->128), swapped operands ----------
            {
                f32x4 acc2[4];
                #pragma unroll
                for (int mt = 0; mt < 4; ++mt) acc2[mt] = bias2q;   // bias folded

                #pragma unroll
                for (int ks = 0; ks < 2; ++ks)
                    #pragma unroll
                    for (int mt = 0; mt < 4; ++mt) {
                        const bf16x8 a = *(const bf16x8*)&A1[((mt * 2 + ks) * 64 + lane) * 8];
                        acc2[mt] = __builtin_amdgcn_mfma_f32_16x16x32_bf16(bw2[ks], a, acc2[mt], 0, 0, 0);
                    }
                // relu + pack 4 consecutive layer-3 k's of one point -> ds_write_b64
                #pragma unroll
                for (int mt = 0; mt < 4; ++mt) {
                    const uint u0 = cvt_pk_bf16(fmaxf(acc2[mt][0], 0.f), fmaxf(acc2[mt][1], 0.f));
                    const uint u1 = cvt_pk_bf16(fmaxf(acc2[mt][2], 0.f), fmaxf(acc2[mt][3], 0.f));
                    const int chunk = (mt * 4 + ks3) * 64 + g3 * 16 + rc;
                    uint2 val; val.x = u0; val.y = u1;
                    *(uint2*)&A3[chunk * 8 + (g & 1) * 4] = val;
                }
            }
            __syncthreads();

            // ---------- Phase D: layer 3 (128->256), ntiles {2w,2w+1}, fused pool ----------
            {
                f32x4 acc3a[4], acc3b[4];
                #pragma unroll
                for (int mt = 0; mt < 4; ++mt) {
                    acc3a[mt] = (f32x4){b3v0, b3v0, b3v0, b3v0};    // bias folded
                    acc3b[mt] = (f32x4){b3v1, b3v1, b3v1, b3v1};
                }
                #pragma unroll
                for (int ks = 0; ks < 4; ++ks) {
                    const bf16x8 bf0 = *(const bf16x8*)(B3P + (((2 * wu + 0) * 4 + ks) * 64 + lane) * 8);
                    const bf16x8 bf1 = *(const bf16x8*)(B3P + (((2 * wu + 1) * 4 + ks) * 64 + lane) * 8);
                    #pragma unroll
                    for (int mt = 0; mt < 4; ++mt) {
                        const bf16x8 a = *(const bf16x8*)&A3[((mt * 4 + ks) * 64 + lane) * 8];
                        acc3a[mt] = __builtin_amdgcn_mfma_f32_16x16x32_bf16(a, bf0, acc3a[mt], 0, 0, 0);
                        acc3b[mt] = __builtin_amdgcn_mfma_f32_16x16x32_bf16(a, bf1, acc3b[mt], 0, 0, 0);
                    }
                }
                float pool0 = 0.f, pool1 = 0.f;   // relu folded into 0-init
                #pragma unroll
                for (int mt = 0; mt < 4; ++mt)
                    #pragma unroll
                    for (int rr = 0; rr < 4; ++rr) {
                        pool0 = fmaxf(pool0, acc3a[mt][rr]);
                        pool1 = fmaxf(pool1, acc3b[mt][rr]);
                    }
                pool0 = fmaxf(pool0, __shfl_xor(pool0, 16, 64));
                pool0 = fmaxf(pool0, __shfl_xor(pool0, 32, 64));
                pool1 = fmaxf(pool1, __shfl_xor(pool1, 16, 64));
                pool1 = fmaxf(pool1, __shfl_xor(pool1, 32, 64));
                if (g == 0) {
                    atomicMax(&featsG[pcur * 256 + (2 * wu + 0) * 16 + rc], __float_as_int(pool0));
                    atomicMax(&featsG[pcur * 256 + (2 * wu + 1) * 16 + rc], __float_as_int(pool1));
                }
            }
            // no 3rd barrier needed: A1 is last read before bar2; A3 last read
            // before the next iteration's bar1.
        }
        q = qn;
    }
}

// One wave per proposal: 5 dot products of length 256.
__global__ __launch_bounds__(256) void heads_kernel(
    const int* __restrict__ featsG,
    const float* __restrict__ Wc, const float* __restrict__ bc,
    const float* __restrict__ Wr, const float* __restrict__ br,
    float* __restrict__ out, int P)
{
    const int tid  = threadIdx.x;
    const int lane = tid & 63;
    const int p    = blockIdx.x * 4 + (tid >> 6);
    if (p >= P) return;

    const int4 vi = *(const int4*)&featsG[p * 256 + lane * 4];
    float v[4] = {__int_as_float(vi.x), __int_as_float(vi.y),
                  __int_as_float(vi.z), __int_as_float(vi.w)};

    const float4 wc = *(const float4*)&Wc[lane * 4];
    float c  = v[0] * wc.x + v[1] * wc.y + v[2] * wc.z + v[3] * wc.w;
    float r0 = 0.f, r1 = 0.f, r2 = 0.f, r3 = 0.f;
    #pragma unroll
    for (int i = 0; i < 4; ++i) {
        const float4 wr = *(const float4*)&Wr[(lane * 4 + i) * 4];
        r0 = fmaf(v[i], wr.x, r0);
        r1 = fmaf(v[i], wr.y, r1);
        r2 = fmaf(v[i], wr.z, r2);
        r3 = fmaf(v[i], wr.w, r3);
    }
    #pragma unroll
    for (int off = 32; off > 0; off >>= 1) {
        c  += __shfl_xor(c,  off, 64);
        r0 += __shfl_xor(r0, off, 64);
        r1 += __shfl_xor(r1, off, 64);
        r2 += __shfl_xor(r2, off, 64);
        r3 += __shfl_xor(r3, off, 64);
    }
    if (lane == 0) {
        out[p]             = c  + bc[0];
        out[P + p * 4 + 0] = r0 + br[0];
        out[P + p * 4 + 1] = r1 + br[1];
        out[P + p * 4 + 2] = r2 + br[2];
        out[P + p * 4 + 3] = r3 + br[3];
    }
}

extern "C" void kernel_launch(void* const* d_in, const int* in_sizes, int n_in,
                              void* d_out, int out_size, void* d_ws, size_t ws_size,
                              hipStream_t stream)
{
    const float* points    = (const float*)d_in[0];
    const int*   lengths   = (const int*)  d_in[1];
    const float* proposals = (const float*)d_in[2];
    const float* W1 = (const float*)d_in[3];
    const float* b1 = (const float*)d_in[4];
    const float* W2 = (const float*)d_in[5];
    const float* b2 = (const float*)d_in[6];
    const float* W3 = (const float*)d_in[7];
    const float* b3 = (const float*)d_in[8];
    const float* Wc = (const float*)d_in[9];
    const float* bc = (const float*)d_in[10];
    const float* Wr = (const float*)d_in[11];
    const float* br = (const float*)d_in[12];
    float* out = (float*)d_out;

    const int P = in_sizes[1];              // 2048
    const int N = in_sizes[0] / (3 * P);    // 256
    const int SMAX = (N + 63) / 64;         // 4
    const int work = P * SMAX;              // 8192
    const int NB   = 2048;                  // persistent-ish blocks

    ushort* B2P    = (ushort*)d_ws;                 // 8192 bf16  (16 KB)
    ushort* B3P    = B2P + 8192;                    // 32768 bf16 (64 KB)
    int*    featsG = (int*)((char*)d_ws + 81920);   // P*256 ints (2 MB)

    hipMemsetAsync(featsG, 0, (size_t)P * 256 * sizeof(int), stream);
    pack_weights<<<dim3(128), dim3(256), 0, stream>>>(W2, W3, B2P, B3P);
    refine_loop<<<dim3(NB), dim3(512), 0, stream>>>(
        points, lengths, proposals, W1, b1, b2, b3, B2P, B3P, featsG,
        P, N, work, NB);
    heads_kernel<<<dim3((P + 3) / 4), dim3(256), 0, stream>>>(
        featsG, Wc, bc, Wr, br, out, P);
}

// Round 6
// 61.032 us; speedup vs baseline: 1.7922x; 1.7922x over previous
//
#include <hip/hip_runtime.h>
#include <hip/hip_bf16.h>

#define MIN_PTS 4

typedef short bf16x8 __attribute__((ext_vector_type(8)));
typedef float f32x4  __attribute__((ext_vector_type(4)));

__device__ __forceinline__ ushort f2bf(float x) {
    unsigned u = __float_as_uint(x);
    u = (u + 0x7fffu + ((u >> 16) & 1u)) >> 16;   // RNE, finite inputs
    return (ushort)u;
}

// v_cvt_pk_bf16_f32: lo -> low 16, hi -> high 16 (RNE)
__device__ __forceinline__ uint cvt_pk_bf16(float lo, float hi) {
    union { __hip_bfloat162 h; uint u; } cv;
    cv.h = __float22bfloat162_rn(make_float2(lo, hi));
    return cv.u;
}

// Pack W2 [64][128] and W3 [128][256] (fp32 row-major, K x N) into bf16
// MFMA B-fragment-linear layout: [ntile][kstep][lane][8], where
// element j of lane l = W[k = 32*ks + 8*(l>>4) + j][col = 16*nt + (l&15)].
__global__ void pack_weights(const float* __restrict__ W2, const float* __restrict__ W3,
                             ushort* __restrict__ B2P, ushort* __restrict__ B3P)
{
    int idx = blockIdx.x * 256 + threadIdx.x;
    if (idx < 8192) {   // W2: 8 ntiles x 2 ksteps x 64 lanes x 8
        int j = idx & 7, l = (idx >> 3) & 63, ks = (idx >> 9) & 1, nt = idx >> 10;
        int k   = ks * 32 + (l >> 4) * 8 + j;
        int col = nt * 16 + (l & 15);
        B2P[idx] = f2bf(W2[k * 128 + col]);
    }
    if (idx < 32768) {  // W3: 16 ntiles x 4 ksteps x 64 lanes x 8
        int j = idx & 7, l = (idx >> 3) & 63, ks = (idx >> 9) & 3, nt = idx >> 11;
        int k   = ks * 32 + (l >> 4) * 8 + j;
        int col = nt * 16 + (l & 15);
        B3P[idx] = f2bf(W3[k * 256 + col]);
    }
}

// Persistent grid-stride blocks (8 waves, 512 thr). One work item = one
// 64-point stripe: q -> p = q>>2, s = q&3. Wave w: layer1 features 8w..8w+7;
// layer2 ntile w; layer3 ntiles {2w, 2w+1}.
__global__ __launch_bounds__(512, 4) void refine_loop(
    const float* __restrict__ points,    // [P][N][3]
    const int*   __restrict__ lengths,   // [P]
    const float* __restrict__ proposals, // [P][6]
    const float* __restrict__ W1, const float* __restrict__ b1,   // [3][64],[64]
    const float* __restrict__ b2,                                  // [128]
    const float* __restrict__ b3,                                  // [256]
    const ushort* __restrict__ B2P, const ushort* __restrict__ B3P,
    int* __restrict__ featsG,            // [P][256] f32 bits, pre-zeroed
    int P, int N, int work, int NB)
{
    __shared__ __align__(16) ushort A1[4096];   // h1 frags [mt(4)][ks(2)][lane][8]
    __shared__ __align__(16) ushort A3[8192];   // h2 frags [mt(4)][ks(4)][lane][8]

    const int tid  = threadIdx.x;
    const int lane = tid & 63;
    const int wu   = __builtin_amdgcn_readfirstlane(tid >> 6);  // wave id, SGPR
    const int rc   = lane & 15;
    const int g    = lane >> 4;

    // ---- loop-invariant state ----
    // layer-1 weights: wave-uniform -> scalar loads, SGPR-resident
    float w1a[8], w1b[8], w1c[8], b1r[8];
    #pragma unroll
    for (int i = 0; i < 8; ++i) {
        const int f = wu * 8 + i;
        w1a[i] = W1[f]; w1b[i] = W1[64 + f]; w1c[i] = W1[128 + f]; b1r[i] = b1[f];
    }
    // per-lane biases (folded into MFMA C-init)
    f32x4 bias2q;
    #pragma unroll
    for (int rr = 0; rr < 4; ++rr) bias2q[rr] = b2[16 * wu + 4 * g + rr];
    const float b3v0 = b3[16 * (2 * wu + 0) + rc];
    const float b3v1 = b3[16 * (2 * wu + 1) + rc];

    // iteration-invariant LDS addresses
    ushort* const a1wr = &A1[(((lane >> 4) * 2 + (wu >> 2)) * 64 + (wu & 3) * 16 + rc) * 8];
    const int ks3 = wu >> 1;                 // (16w+4g)>>5
    const int g3  = (2 * wu + (g >> 1)) & 3; // ((16w+4g)>>3)&3

    // ---- prefetch item q (raw values only; uniform parts stay scalar) ----
    int q = blockIdx.x;
    int   lenC;
    float prC[6];          // raw proposal row (block-uniform -> SGPRs)
    float p0C, p1C, p2C;   // per-lane point triple (3 VGPRs)
    {
        const int pp = q >> 2, ss = q & 3;
        lenC = lengths[pp];
        #pragma unroll
        for (int i = 0; i < 6; ++i) prC[i] = proposals[pp * 6 + i];
        const int jj = min(ss * 64 + lane, max(lenC, 1) - 1);
        const float* pt = points + ((long)pp * N + jj) * 3;
        p0C = pt[0]; p1C = pt[1]; p2C = pt[2];
    }

    while (q < work) {
        const int   pcur   = q >> 2;
        const bool  active = (lenC >= MIN_PTS) && ((q & 3) * 64 < lenC);
        float pr[6];
        #pragma unroll
        for (int i = 0; i < 6; ++i) pr[i] = prC[i];
        const float p0 = p0C, p1 = p1C, p2 = p2C;

        const int qn = q + NB;
        if (qn < work) {   // prefetch next item (hides under MFMA phases)
            const int pp = qn >> 2, ss = qn & 3;
            lenC = lengths[pp];
            #pragma unroll
            for (int i = 0; i < 6; ++i) prC[i] = proposals[pp * 6 + i];
            const int jj = min(ss * 64 + lane, max(lenC, 1) - 1);
            const float* pt = points + ((long)pp * N + jj) * 3;
            p0C = pt[0]; p1C = pt[1]; p2C = pt[2];
        }

        if (active) {   // block-uniform branch (q is block-uniform)
            // ---------- Phase A: layer 1 (3->64), one uint4 LDS write/lane ----------
            {
                const float rx = __builtin_amdgcn_rcpf(fmaf(pr[3], 0.5f, 1e-6f));
                const float ry = __builtin_amdgcn_rcpf(fmaf(pr[4], 0.5f, 1e-6f));
                const float rz = __builtin_amdgcn_rcpf(fmaf(pr[5], 0.5f, 1e-6f));
                const float x0 = (p0 - pr[0]) * rx;
                const float x1 = (p1 - pr[1]) * ry;
                const float x2 = (p2 - pr[2]) * rz;
                float v[8];
                #pragma unroll
                for (int i = 0; i < 8; ++i)
                    v[i] = fmaxf(fmaf(x0, w1a[i], fmaf(x1, w1b[i], fmaf(x2, w1c[i], b1r[i]))), 0.f);
                uint4 qq;
                qq.x = cvt_pk_bf16(v[0], v[1]);
                qq.y = cvt_pk_bf16(v[2], v[3]);
                qq.z = cvt_pk_bf16(v[4], v[5]);
                qq.w = cvt_pk_bf16(v[6], v[7]);
                *(uint4*)a1wr = qq;
            }
            __syncthreads();

            // ---------- Phase B: layer 2 (64->128), swapped operands ----------
            {
                f32x4 acc2[4];
                #pragma unroll
                for (int mt = 0; mt < 4; ++mt) acc2[mt] = bias2q;   // bias folded

                #pragma unroll
                for (int ks = 0; ks < 2; ++ks) {
                    const bf16x8 bw = *(const bf16x8*)(B2P + ((wu * 2 + ks) * 64 + lane) * 8);
                    #pragma unroll
                    for (int mt = 0; mt < 4; ++mt) {
                        const bf16x8 a = *(const bf16x8*)&A1[((mt * 2 + ks) * 64 + lane) * 8];
                        acc2[mt] = __builtin_amdgcn_mfma_f32_16x16x32_bf16(bw, a, acc2[mt], 0, 0, 0);
                    }
                }
                // relu + pack 4 consecutive layer-3 k's of one point -> ds_write_b64
                #pragma unroll
                for (int mt = 0; mt < 4; ++mt) {
                    const uint u0 = cvt_pk_bf16(fmaxf(acc2[mt][0], 0.f), fmaxf(acc2[mt][1], 0.f));
                    const uint u1 = cvt_pk_bf16(fmaxf(acc2[mt][2], 0.f), fmaxf(acc2[mt][3], 0.f));
                    const int chunk = (mt * 4 + ks3) * 64 + g3 * 16 + rc;
                    uint2 val; val.x = u0; val.y = u1;
                    *(uint2*)&A3[chunk * 8 + (g & 1) * 4] = val;
                }
            }
            __syncthreads();

            // ---------- Phase D: layer 3 (128->256), ntiles {2w,2w+1}, fused pool ----------
            {
                f32x4 acc3a[4], acc3b[4];
                #pragma unroll
                for (int mt = 0; mt < 4; ++mt) {
                    acc3a[mt] = (f32x4){b3v0, b3v0, b3v0, b3v0};    // bias folded
                    acc3b[mt] = (f32x4){b3v1, b3v1, b3v1, b3v1};
                }
                #pragma unroll
                for (int ks = 0; ks < 4; ++ks) {
                    const bf16x8 bf0 = *(const bf16x8*)(B3P + (((2 * wu + 0) * 4 + ks) * 64 + lane) * 8);
                    const bf16x8 bf1 = *(const bf16x8*)(B3P + (((2 * wu + 1) * 4 + ks) * 64 + lane) * 8);
                    #pragma unroll
                    for (int mt = 0; mt < 4; ++mt) {
                        const bf16x8 a = *(const bf16x8*)&A3[((mt * 4 + ks) * 64 + lane) * 8];
                        acc3a[mt] = __builtin_amdgcn_mfma_f32_16x16x32_bf16(a, bf0, acc3a[mt], 0, 0, 0);
                        acc3b[mt] = __builtin_amdgcn_mfma_f32_16x16x32_bf16(a, bf1, acc3b[mt], 0, 0, 0);
                    }
                }
                float pool0 = 0.f, pool1 = 0.f;   // relu folded into 0-init
                #pragma unroll
                for (int mt = 0; mt < 4; ++mt)
                    #pragma unroll
                    for (int rr = 0; rr < 4; ++rr) {
                        pool0 = fmaxf(pool0, acc3a[mt][rr]);
                        pool1 = fmaxf(pool1, acc3b[mt][rr]);
                    }
                pool0 = fmaxf(pool0, __shfl_xor(pool0, 16, 64));
                pool0 = fmaxf(pool0, __shfl_xor(pool0, 32, 64));
                pool1 = fmaxf(pool1, __shfl_xor(pool1, 16, 64));
                pool1 = fmaxf(pool1, __shfl_xor(pool1, 32, 64));
                if (g == 0) {
                    atomicMax(&featsG[pcur * 256 + (2 * wu + 0) * 16 + rc], __float_as_int(pool0));
                    atomicMax(&featsG[pcur * 256 + (2 * wu + 1) * 16 + rc], __float_as_int(pool1));
                }
            }
            // no 3rd barrier needed: A1 is last read before bar2; A3 last read
            // before the next iteration's bar1.
        }
        q = qn;
    }
}

// One wave per proposal: 5 dot products of length 256.
__global__ __launch_bounds__(256) void heads_kernel(
    const int* __restrict__ featsG,
    const float* __restrict__ Wc, const float* __restrict__ bc,
    const float* __restrict__ Wr, const float* __restrict__ br,
    float* __restrict__ out, int P)
{
    const int tid  = threadIdx.x;
    const int lane = tid & 63;
    const int p    = blockIdx.x * 4 + (tid >> 6);
    if (p >= P) return;

    const int4 vi = *(const int4*)&featsG[p * 256 + lane * 4];
    float v[4] = {__int_as_float(vi.x), __int_as_float(vi.y),
                  __int_as_float(vi.z), __int_as_float(vi.w)};

    const float4 wc = *(const float4*)&Wc[lane * 4];
    float c  = v[0] * wc.x + v[1] * wc.y + v[2] * wc.z + v[3] * wc.w;
    float r0 = 0.f, r1 = 0.f, r2 = 0.f, r3 = 0.f;
    #pragma unroll
    for (int i = 0; i < 4; ++i) {
        const float4 wr = *(const float4*)&Wr[(lane * 4 + i) * 4];
        r0 = fmaf(v[i], wr.x, r0);
        r1 = fmaf(v[i], wr.y, r1);
        r2 = fmaf(v[i], wr.z, r2);
        r3 = fmaf(v[i], wr.w, r3);
    }
    #pragma unroll
    for (int off = 32; off > 0; off >>= 1) {
        c  += __shfl_xor(c,  off, 64);
        r0 += __shfl_xor(r0, off, 64);
        r1 += __shfl_xor(r1, off, 64);
        r2 += __shfl_xor(r2, off, 64);
        r3 += __shfl_xor(r3, off, 64);
    }
    if (lane == 0) {
        out[p]             = c  + bc[0];
        out[P + p * 4 + 0] = r0 + br[0];
        out[P + p * 4 + 1] = r1 + br[1];
        out[P + p * 4 + 2] = r2 + br[2];
        out[P + p * 4 + 3] = r3 + br[3];
    }
}

extern "C" void kernel_launch(void* const* d_in, const int* in_sizes, int n_in,
                              void* d_out, int out_size, void* d_ws, size_t ws_size,
                              hipStream_t stream)
{
    const float* points    = (const float*)d_in[0];
    const int*   lengths   = (const int*)  d_in[1];
    const float* proposals = (const float*)d_in[2];
    const float* W1 = (const float*)d_in[3];
    const float* b1 = (const float*)d_in[4];
    const float* W2 = (const float*)d_in[5];
    const float* b2 = (const float*)d_in[6];
    const float* W3 = (const float*)d_in[7];
    const float* b3 = (const float*)d_in[8];
    const float* Wc = (const float*)d_in[9];
    const float* bc = (const float*)d_in[10];
    const float* Wr = (const float*)d_in[11];
    const float* br = (const float*)d_in[12];
    float* out = (float*)d_out;

    const int P = in_sizes[1];              // 2048
    const int N = in_sizes[0] / (3 * P);    // 256
    const int SMAX = (N + 63) / 64;         // 4
    const int work = P * SMAX;              // 8192
    const int NB   = 2048;                  // persistent-ish blocks

    ushort* B2P    = (ushort*)d_ws;                 // 8192 bf16  (16 KB)
    ushort* B3P    = B2P + 8192;                    // 32768 bf16 (64 KB)
    int*    featsG = (int*)((char*)d_ws + 81920);   // P*256 ints (2 MB)

    hipMemsetAsync(featsG, 0, (size_t)P * 256 * sizeof(int), stream);
    pack_weights<<<dim3(128), dim3(256), 0, stream>>>(W2, W3, B2P, B3P);
    refine_loop<<<dim3(NB), dim3(512), 0, stream>>>(
        points, lengths, proposals, W1, b1, b2, b3, B2P, B3P, featsG,
        P, N, work, NB);
    heads_kernel<<<dim3((P + 3) / 4), dim3(256), 0, stream>>>(
        featsG, Wc, bc, Wr, br, out, P);
}